// Round 3
// baseline (199.800 us; speedup 1.0000x reference)
//
#include <hip/hip_runtime.h>
#include <cfloat>
#include <cmath>

#define BB 128
#define MM 50
#define AA 2100
#define NC 30
#define DCH 64
#define CHT 94        // total channels = 64 + 30
#define GPB 525       // anchor groups per batch = AA/4
#define LOSS_BLOCK 128
#define LOSS_GRID ((BB * GPB) / LOSS_BLOCK)   // 525, exact

// One wave per (b,m): argmin over 2100 anchors (squared dist), write packed
// code = best | (cls<<16), or 0xFFFFFFFF if invalid. gtid 0 also zeroes the
// accumulators (stream-ordered before loss_kernel).
__global__ void assign_kernel(const float* __restrict__ txy,
                              const int* __restrict__ tcls,
                              const unsigned char* __restrict__ valid,
                              const float* __restrict__ anchors,
                              unsigned int* __restrict__ codes,
                              double* __restrict__ sums,
                              unsigned int* __restrict__ cnt,
                              unsigned int* __restrict__ ticket) {
    int gtid = blockIdx.x * blockDim.x + threadIdx.x;
    if (gtid == 0) { sums[0] = 0.0; sums[1] = 0.0; *cnt = 0u; *ticket = 0u; }
    int pair = gtid >> 6;
    int lane = gtid & 63;
    if (pair >= BB * MM) return;
    if (!valid[pair]) {
        if (lane == 0) codes[pair] = 0xFFFFFFFFu;
        return;
    }

    float cx = txy[pair * 2 + 0] * 320.0f;
    float cy = txy[pair * 2 + 1] * 320.0f;

    const float2* __restrict__ anc = (const float2*)anchors;
    float bd = FLT_MAX;
    int   bi = 0x7fffffff;
    #pragma unroll 4
    for (int a = lane; a < AA; a += 64) {
        float2 p = anc[a];
        float dx = p.x - cx;
        float dy = p.y - cy;
        float d = dx * dx + dy * dy;          // squared dist: same argmin
        if (d < bd) { bd = d; bi = a; }       // strict < keeps lowest index
    }
    for (int off = 32; off > 0; off >>= 1) {  // tie-break on lowest index
        float od = __shfl_xor(bd, off);
        int   oi = __shfl_xor(bi, off);
        if (od < bd || (od == bd && oi < bi)) { bd = od; bi = oi; }
    }
    if (lane == 0)
        codes[pair] = (unsigned int)bi | ((unsigned int)tcls[pair] << 16);
}

__device__ __forceinline__ float huber_of_mean(float s) {
    float e = s * (1.0f / 64.0f) - 1.0f;
    float ae = fabsf(e);
    return (ae <= 1.0f) ? 0.5f * e * e : ae - 0.5f;
}

// One thread per 4 consecutive anchors of one batch. float4 loads for the 30
// class channels; per-anchor class/fg masks rebuilt from codes[b*50..+50]
// (L1-resident). Box huber only where fg. Grid-wide finalize via ticket.
__global__ __launch_bounds__(LOSS_BLOCK)
void loss_kernel(const float* __restrict__ pred,
                 const unsigned int* __restrict__ codes,
                 double* __restrict__ sums,        // [0]=cls num, [1]=box num
                 unsigned int* __restrict__ cnt,
                 unsigned int* __restrict__ ticket,
                 float* __restrict__ out) {
    int idx = blockIdx.x * LOSS_BLOCK + threadIdx.x;   // exact: 67200 threads
    int b = idx / GPB;
    int g = idx - b * GPB;
    int a0 = g * 4;
    const float* __restrict__ pb = pred + (size_t)b * CHT * AA;

    // 30 float4 loads issued back-to-back (480 B/thread in flight)
    const float* __restrict__ pc = pb + (size_t)DCH * AA + a0;
    float4 xs[NC];
    #pragma unroll
    for (int c = 0; c < NC; ++c)
        xs[c] = *(const float4*)(pc + (size_t)c * AA);

    // rebuild per-anchor masks (bit c = class c present, bit31 = fg)
    unsigned int mw0 = 0, mw1 = 0, mw2 = 0, mw3 = 0;
    const unsigned int* __restrict__ cb = codes + b * MM;
    #pragma unroll 5
    for (int m = 0; m < MM; ++m) {
        unsigned int code = cb[m];
        if (code != 0xFFFFFFFFu) {
            int best = (int)(code & 0xFFFFu);
            unsigned int bit = (1u << (code >> 16)) | 0x80000000u;
            unsigned int d = (unsigned int)(best - a0);
            if (d < 4u) {
                if (d == 0u) mw0 |= bit;
                else if (d == 1u) mw1 |= bit;
                else if (d == 2u) mw2 |= bit;
                else mw3 |= bit;
            }
        }
    }

    // classification BCE: softplus(x) - t*x  (t in {0,1})
    float acc = 0.0f;
    #pragma unroll
    for (int c = 0; c < NC; ++c) {
        float4 v = xs[c];
        float sp;
        sp = fmaxf(v.x, 0.f) + __logf(1.f + __expf(-fabsf(v.x)));
        acc += sp - (((mw0 >> c) & 1u) ? v.x : 0.f);
        sp = fmaxf(v.y, 0.f) + __logf(1.f + __expf(-fabsf(v.y)));
        acc += sp - (((mw1 >> c) & 1u) ? v.y : 0.f);
        sp = fmaxf(v.z, 0.f) + __logf(1.f + __expf(-fabsf(v.z)));
        acc += sp - (((mw2 >> c) & 1u) ? v.z : 0.f);
        sp = fmaxf(v.w, 0.f) + __logf(1.f + __expf(-fabsf(v.w)));
        acc += sp - (((mw3 >> c) & 1u) ? v.w : 0.f);
    }

    // box loss at fg anchors (~5% of threads take the branch)
    float box = 0.0f;
    unsigned int nfg = 0;
    if ((mw0 | mw1 | mw2 | mw3) & 0x80000000u) {
        float4 s = make_float4(0.f, 0.f, 0.f, 0.f);
        #pragma unroll 8
        for (int ch = 0; ch < DCH; ++ch) {
            float4 v = *(const float4*)(pb + (size_t)ch * AA + a0);
            s.x += v.x; s.y += v.y; s.z += v.z; s.w += v.w;
        }
        if (mw0 >> 31) { box += huber_of_mean(s.x); nfg++; }
        if (mw1 >> 31) { box += huber_of_mean(s.y); nfg++; }
        if (mw2 >> 31) { box += huber_of_mean(s.z); nfg++; }
        if (mw3 >> 31) { box += huber_of_mean(s.w); nfg++; }
    }

    // wave reduce
    for (int off = 32; off > 0; off >>= 1) {
        acc += __shfl_down(acc, off);
        box += __shfl_down(box, off);
        nfg += __shfl_down(nfg, off);
    }
    __shared__ float s_cls[2];
    __shared__ float s_box[2];
    __shared__ unsigned int s_fg[2];
    int lane = threadIdx.x & 63;
    int w = threadIdx.x >> 6;
    if (lane == 0) { s_cls[w] = acc; s_box[w] = box; s_fg[w] = nfg; }
    __syncthreads();

    if (threadIdx.x == 0) {
        atomicAdd(&sums[0], (double)((double)s_cls[0] + (double)s_cls[1]));
        atomicAdd(&sums[1], (double)((double)s_box[0] + (double)s_box[1]));
        unsigned int tf = s_fg[0] + s_fg[1];
        if (tf) atomicAdd(cnt, tf);
        __threadfence();
        unsigned int old = atomicAdd(ticket, 1u);
        if (old == (unsigned int)(LOSS_GRID - 1)) {
            // last block: all other blocks' atomics are visible (L2)
            double tc = atomicAdd(&sums[0], 0.0);
            double tb = atomicAdd(&sums[1], 0.0);
            unsigned int c = atomicAdd(cnt, 0u);
            out[0] = (c > 0) ? (float)(tb / (double)c) : 0.0f;         // loss_box
            out[1] = (float)(tc / (double)((size_t)BB * NC * AA));     // loss_cls
        }
    }
}

extern "C" void kernel_launch(void* const* d_in, const int* in_sizes, int n_in,
                              void* d_out, int out_size, void* d_ws, size_t ws_size,
                              hipStream_t stream) {
    const float*         pred    = (const float*)d_in[0];
    const int*           tcls    = (const int*)d_in[1];
    const float*         txy     = (const float*)d_in[2];
    const unsigned char* valid   = (const unsigned char*)d_in[3];  // numpy bool
    const float*         anchors = (const float*)d_in[4];
    float* out = (float*)d_out;

    // ws layout: sums[2] (f64, 16 B) | cnt | ticket | codes[6400]
    double*       sums   = (double*)d_ws;
    unsigned int* cnt    = (unsigned int*)((char*)d_ws + 16);
    unsigned int* ticket = (unsigned int*)((char*)d_ws + 20);
    unsigned int* codes  = (unsigned int*)((char*)d_ws + 24);

    {   // assignment: one wave per (b,m); also zeroes accumulators
        int threads = BB * MM * 64;
        int block = 256;
        int grid = (threads + block - 1) / block;
        assign_kernel<<<grid, block, 0, stream>>>(txy, tcls, valid, anchors,
                                                  codes, sums, cnt, ticket);
    }
    // loss + fused finalize: one thread per 4 anchors
    loss_kernel<<<LOSS_GRID, LOSS_BLOCK, 0, stream>>>(pred, codes, sums, cnt,
                                                      ticket, out);
}

// Round 4
// 168.928 us; speedup vs baseline: 1.1827x; 1.1827x over previous
//
#include <hip/hip_runtime.h>
#include <cfloat>
#include <cmath>

#define BB 128
#define MM 50
#define AA 2100
#define NC 30
#define DCH 64
#define CHT 94                      // total channels = 64 + 30
#define GPB 525                     // 4-anchor groups per batch = AA/4
#define TOTG (BB * GPB)             // 67200 groups
#define HCLS 15                     // classes per half-thread
#define LOSS_BLOCK 256
#define LOSS_GRID ((2 * TOTG) / LOSS_BLOCK)   // 525, exact
#define NSLOT 64                    // partial-sum slots (spread atomics)

// One wave per (b,m): argmin over 2100 anchors (squared dist), write packed
// code = best | (cls<<16), or 0xFFFFFFFF if invalid. First wave also zeroes
// the partial-sum slots + ticket (stream-ordered before loss_kernel).
__global__ void assign_kernel(const float* __restrict__ txy,
                              const int* __restrict__ tcls,
                              const unsigned char* __restrict__ valid,
                              const float* __restrict__ anchors,
                              unsigned int* __restrict__ codes,
                              double* __restrict__ pcls,
                              double* __restrict__ pbox,
                              unsigned int* __restrict__ pcnt,
                              unsigned int* __restrict__ ticket) {
    int gtid = blockIdx.x * blockDim.x + threadIdx.x;
    if (gtid < NSLOT) { pcls[gtid] = 0.0; pbox[gtid] = 0.0; pcnt[gtid] = 0u; }
    if (gtid == 0) *ticket = 0u;

    int pair = gtid >> 6;
    int lane = gtid & 63;
    if (pair >= BB * MM) return;
    if (!valid[pair]) {
        if (lane == 0) codes[pair] = 0xFFFFFFFFu;
        return;
    }

    float cx = txy[pair * 2 + 0] * 320.0f;
    float cy = txy[pair * 2 + 1] * 320.0f;

    const float2* __restrict__ anc = (const float2*)anchors;
    float bd = FLT_MAX;
    int   bi = 0x7fffffff;
    #pragma unroll 4
    for (int a = lane; a < AA; a += 64) {
        float2 p = anc[a];
        float dx = p.x - cx;
        float dy = p.y - cy;
        float d = dx * dx + dy * dy;          // squared dist: same argmin
        if (d < bd) { bd = d; bi = a; }       // strict < keeps lowest index
    }
    for (int off = 32; off > 0; off >>= 1) {  // tie-break on lowest index
        float od = __shfl_xor(bd, off);
        int   oi = __shfl_xor(bi, off);
        if (od < bd || (od == bd && oi < bi)) { bd = od; bi = oi; }
    }
    if (lane == 0)
        codes[pair] = (unsigned int)bi | ((unsigned int)tcls[pair] << 16);
}

__device__ __forceinline__ float huber_of_mean(float s) {
    float e = s * (1.0f / 64.0f) - 1.0f;
    float ae = fabsf(e);
    return (ae <= 1.0f) ? 0.5f * e * e : ae - 0.5f;
}

// Thread = (half h, batch b, 4-anchor group g): 15 class channels as float4
// loads (240 B in flight/thread; 2100 waves total -> BW-saturating).
// h==0 threads additionally own the box loss for their 4 anchors.
// Per-block partials go to 64 spread slots (f64 atomics, ~8-deep chains);
// last block (ticket) reduces the slots and writes out.
__global__ __launch_bounds__(LOSS_BLOCK)
void loss_kernel(const float* __restrict__ pred,
                 const unsigned int* __restrict__ codes,
                 double* __restrict__ pcls,
                 double* __restrict__ pbox,
                 unsigned int* __restrict__ pcnt,
                 unsigned int* __restrict__ ticket,
                 float* __restrict__ out) {
    int tid = blockIdx.x * LOSS_BLOCK + threadIdx.x;   // exact: 134400 threads
    int h  = tid / TOTG;                 // 0 or 1 (channel half)
    int gi = tid - h * TOTG;
    int b  = gi / GPB;
    int g  = gi - b * GPB;
    int a0 = g * 4;
    int c0 = h * HCLS;
    const float* __restrict__ pb = pred + (size_t)b * CHT * AA;

    // 15 float4 loads issued back-to-back
    const float* __restrict__ pc = pb + (size_t)(DCH + c0) * AA + a0;
    float4 xs[HCLS];
    #pragma unroll
    for (int c = 0; c < HCLS; ++c)
        xs[c] = *(const float4*)(pc + (size_t)c * AA);

    // rebuild per-anchor masks (bit c = class c0+c present, bit31 = fg);
    // overlaps the loads above
    unsigned int mw0 = 0, mw1 = 0, mw2 = 0, mw3 = 0;
    const unsigned int* __restrict__ cb = codes + b * MM;
    #pragma unroll 5
    for (int m = 0; m < MM; ++m) {
        unsigned int code = cb[m];
        if (code != 0xFFFFFFFFu) {
            unsigned int d = (code & 0xFFFFu) - (unsigned int)a0;
            if (d < 4u) {
                int cc = (int)(code >> 16) - c0;
                unsigned int bit = 0x80000000u |
                    ((cc >= 0 && cc < HCLS) ? (1u << cc) : 0u);
                if (d == 0u) mw0 |= bit;
                else if (d == 1u) mw1 |= bit;
                else if (d == 2u) mw2 |= bit;
                else mw3 |= bit;
            }
        }
    }

    // box loss (h==0 threads at fg anchors, ~5% of them): issue loads now so
    // they pipeline; BCE compute below covers their latency for other waves
    float box = 0.0f;
    unsigned int nfg = 0;
    if (h == 0 && ((mw0 | mw1 | mw2 | mw3) >> 31)) {
        float4 s = make_float4(0.f, 0.f, 0.f, 0.f);
        #pragma unroll 8
        for (int ch = 0; ch < DCH; ++ch) {
            float4 v = *(const float4*)(pb + (size_t)ch * AA + a0);
            s.x += v.x; s.y += v.y; s.z += v.z; s.w += v.w;
        }
        if (mw0 >> 31) { box += huber_of_mean(s.x); nfg++; }
        if (mw1 >> 31) { box += huber_of_mean(s.y); nfg++; }
        if (mw2 >> 31) { box += huber_of_mean(s.z); nfg++; }
        if (mw3 >> 31) { box += huber_of_mean(s.w); nfg++; }
    }

    // classification BCE: softplus(x) - t*x  (t in {0,1})
    float acc = 0.0f;
    #pragma unroll
    for (int c = 0; c < HCLS; ++c) {
        float4 v = xs[c];
        float sp;
        sp = fmaxf(v.x, 0.f) + __logf(1.f + __expf(-fabsf(v.x)));
        acc += sp - (((mw0 >> c) & 1u) ? v.x : 0.f);
        sp = fmaxf(v.y, 0.f) + __logf(1.f + __expf(-fabsf(v.y)));
        acc += sp - (((mw1 >> c) & 1u) ? v.y : 0.f);
        sp = fmaxf(v.z, 0.f) + __logf(1.f + __expf(-fabsf(v.z)));
        acc += sp - (((mw2 >> c) & 1u) ? v.z : 0.f);
        sp = fmaxf(v.w, 0.f) + __logf(1.f + __expf(-fabsf(v.w)));
        acc += sp - (((mw3 >> c) & 1u) ? v.w : 0.f);
    }

    // wave reduce
    for (int off = 32; off > 0; off >>= 1) {
        acc += __shfl_down(acc, off);
        box += __shfl_down(box, off);
        nfg += __shfl_down(nfg, off);
    }
    __shared__ float s_cls[4];
    __shared__ float s_box[4];
    __shared__ unsigned int s_fg[4];
    __shared__ int is_last;
    int lane = threadIdx.x & 63;
    int w = threadIdx.x >> 6;
    if (lane == 0) { s_cls[w] = acc; s_box[w] = box; s_fg[w] = nfg; }
    __syncthreads();

    if (threadIdx.x == 0) {
        int slot = blockIdx.x & (NSLOT - 1);
        double tc = (double)s_cls[0] + s_cls[1] + s_cls[2] + s_cls[3];
        double tb = (double)s_box[0] + s_box[1] + s_box[2] + s_box[3];
        unsigned int tf = s_fg[0] + s_fg[1] + s_fg[2] + s_fg[3];
        atomicAdd(&pcls[slot], tc);
        if (tb != 0.0) atomicAdd(&pbox[slot], tb);
        if (tf) atomicAdd(&pcnt[slot], tf);
        __threadfence();
        unsigned int old = atomicAdd(ticket, 1u);
        is_last = (old == (unsigned int)(LOSS_GRID - 1));
    }
    __syncthreads();

    // last block, first wave: reduce the 64 slots (atomic readback = coherent)
    if (is_last && threadIdx.x < NSLOT) {
        double cs = atomicAdd(&pcls[threadIdx.x], 0.0);
        double bs = atomicAdd(&pbox[threadIdx.x], 0.0);
        unsigned int ct = atomicAdd(&pcnt[threadIdx.x], 0u);
        for (int off = 32; off > 0; off >>= 1) {
            cs += __shfl_down(cs, off);
            bs += __shfl_down(bs, off);
            ct += __shfl_down(ct, off);
        }
        if (threadIdx.x == 0) {
            out[0] = (ct > 0) ? (float)(bs / (double)ct) : 0.0f;        // loss_box
            out[1] = (float)(cs / (double)((size_t)BB * NC * AA));      // loss_cls
        }
    }
}

extern "C" void kernel_launch(void* const* d_in, const int* in_sizes, int n_in,
                              void* d_out, int out_size, void* d_ws, size_t ws_size,
                              hipStream_t stream) {
    const float*         pred    = (const float*)d_in[0];
    const int*           tcls    = (const int*)d_in[1];
    const float*         txy     = (const float*)d_in[2];
    const unsigned char* valid   = (const unsigned char*)d_in[3];  // numpy bool
    const float*         anchors = (const float*)d_in[4];
    float* out = (float*)d_out;

    // ws layout: pcls[64] f64 | pbox[64] f64 | pcnt[64] u32 | ticket | codes[6400]
    double*       pcls   = (double*)d_ws;
    double*       pbox   = (double*)((char*)d_ws + 512);
    unsigned int* pcnt   = (unsigned int*)((char*)d_ws + 1024);
    unsigned int* ticket = (unsigned int*)((char*)d_ws + 1280);
    unsigned int* codes  = (unsigned int*)((char*)d_ws + 1536);

    {   // assignment: one wave per (b,m); also zeroes partials/ticket
        int threads = BB * MM * 64;
        int block = 256;
        int grid = (threads + block - 1) / block;
        assign_kernel<<<grid, block, 0, stream>>>(txy, tcls, valid, anchors,
                                                  codes, pcls, pbox, pcnt, ticket);
    }
    // loss + fused finalize
    loss_kernel<<<LOSS_GRID, LOSS_BLOCK, 0, stream>>>(pred, codes, pcls, pbox,
                                                      pcnt, ticket, out);
}